// Round 12
// baseline (287.475 us; speedup 1.0000x reference)
//
#include <hip/hip_runtime.h>

typedef unsigned short u16;
typedef unsigned int u32;
typedef short short8 __attribute__((ext_vector_type(8)));
typedef short short4v __attribute__((ext_vector_type(4)));
typedef float floatx4 __attribute__((ext_vector_type(4)));

#define NE 800000
#define NNODES 50000
#define NBLK 196  // ceil(50000/256)

// edge_kernel grid: 1536 = resident set (6 blocks/CU x 256, proven R6).
// LAWS from this session:
//  - R2/R7: never force min-waves via __launch_bounds__ 2nd arg (spills).
//  - R10: never use a global-atomic work queue (contended device-scope RMW
//    round-trip stalls every wave; edge 72.8 -> 725us).
//  - R9: direct register-gather loses to LDS staging at matched grid (83 vs 72.8).
//  - R8: inline-asm cvt in edge epilogues regresses (scheduling); bit-trick there.
//  - R11: non-edge total carries +-5-8us run noise; trust per-kernel counters.
#define EDGE_GRID 1536

#define LDS_FENCE() __asm__ volatile("s_waitcnt lgkmcnt(0)" ::: "memory")

// ---------------------------------------------------------------------------
// bf16 conversions. Two flavors, each where it measured fastest:
//  - f2bf (bit-trick RNE): edge epilogues — schedulable plain VALU.
//  - f2bf2 (v_cvt_pk_bf16_f32 pair asm): bulk packs in prep/node — R8 ~-10us.
// Both RNE: bit-identical results.
// ---------------------------------------------------------------------------
__device__ __forceinline__ u16 f2bf(float f) {
    union { float f; unsigned int i; } v; v.f = f;
    return (u16)((v.i + 0x7fffu + ((v.i >> 16) & 1u)) >> 16);
}
__device__ __forceinline__ u32 f2bf2(float lo, float hi) {  // [lo | hi<<16]
    u32 r;
    asm("v_cvt_pk_bf16_f32 %0, %1, %2" : "=v"(r) : "v"(lo), "v"(hi));
    return r;
}
__device__ __forceinline__ float bf2f(u16 u) {
    union { unsigned int i; float f; } v; v.i = ((unsigned int)u) << 16; return v.f;
}
__device__ __forceinline__ short8 pack8(const float4 a, const float4 b) {
    union { short8 s; u32 u[4]; } o;
    o.u[0] = f2bf2(a.x, a.y);
    o.u[1] = f2bf2(a.z, a.w);
    o.u[2] = f2bf2(b.x, b.y);
    o.u[3] = f2bf2(b.z, b.w);
    return o.s;
}
__device__ __forceinline__ short8 ld8_bf(const float* __restrict__ p) {
    return pack8(*(const float4*)p, *(const float4*)(p + 4));
}

#define MFMA16(a, b, c) __builtin_amdgcn_mfma_f32_16x16x32_bf16(a, b, c, 0, 0, 0)

// ---------------------------------------------------------------------------
// prep: dst histogram (atomics) + x -> bf16 conversion + agg zeroing, merged.
// ---------------------------------------------------------------------------
__global__ __launch_bounds__(256) void prep_kernel(
    const float* __restrict__ x, const int* __restrict__ ei,
    int* __restrict__ hist, u16* __restrict__ xbf, float* __restrict__ agg)
{
    const int id = blockIdx.x * 256 + threadIdx.x;
    if (id < NE) {
        atomicAdd(&hist[ei[NE + id]], 1);
        // zero agg: 3.2M floats = 800k float4 stores, one per thread
        float4 z; z.x = 0.f; z.y = 0.f; z.z = 0.f; z.w = 0.f;
        *(float4*)&agg[(size_t)id * 4] = z;
    }
    if (id < NNODES * 8) {  // 400000 threads x 8 elems = 3.2M
        *(short8*)&xbf[(size_t)id * 8] = ld8_bf(x + (size_t)id * 8);
    }
}

// per-block exclusive scan (shuffle), local excl + block total
__global__ __launch_bounds__(256) void scan1_kernel(
    const int* __restrict__ hist, int* __restrict__ cursor, int* __restrict__ bsum)
{
    const int i = blockIdx.x * 256 + threadIdx.x;
    const int lane = threadIdx.x & 63;
    const int w = threadIdx.x >> 6;
    const int v = (i < NNODES) ? hist[i] : 0;
    int inc = v;
    #pragma unroll
    for (int o = 1; o < 64; o <<= 1) {
        const int tt = __shfl_up(inc, o);
        if (lane >= o) inc += tt;
    }
    __shared__ int ws[4];
    if (lane == 63) ws[w] = inc;
    __syncthreads();
    int add = 0;
    for (int j = 0; j < w; ++j) add += ws[j];
    const int excl = inc - v + add;
    if (i < NNODES) cursor[i] = excl;
    if (threadIdx.x == 255) bsum[blockIdx.x] = excl + v;
}

// scatter: ONE 8-byte packed record per edge: (.y = src<<16|dst, .x = e).
// The 196-chunk-total exclusive scan is recomputed locally per block in LDS.
__global__ __launch_bounds__(256) void scatter_kernel(
    const int* __restrict__ ei, int* __restrict__ cursor,
    const int* __restrict__ bsum, uint2* __restrict__ sde)
{
    __shared__ int bsx[256];
    __shared__ int ws[4];
    {
        const int tid = threadIdx.x;
        const int lane = tid & 63;
        const int w = tid >> 6;
        const int v = (tid < NBLK) ? bsum[tid] : 0;
        int inc = v;
        #pragma unroll
        for (int o = 1; o < 64; o <<= 1) {
            const int tt = __shfl_up(inc, o);
            if (lane >= o) inc += tt;
        }
        if (lane == 63) ws[w] = inc;
        __syncthreads();
        int add = 0;
        for (int j = 0; j < w; ++j) add += ws[j];
        bsx[tid] = inc - v + add;
    }
    __syncthreads();

    const int e = blockIdx.x * 256 + threadIdx.x;
    if (e < NE) {
        const int dst = ei[NE + e];
        const int p = atomicAdd(&cursor[dst], 1) + bsx[dst >> 8];
        uint2 v;
        v.x = (u32)e;
        v.y = ((u32)ei[e] << 16) | (u32)dst;
        sde[p] = v;
    }
}

// ---------------------------------------------------------------------------
// Edge kernel (R6/R11 structure + register-resident dst reduction):
//   A1[16x(96 pad 104)] = [xbf[src] copy | bf16(edge_feat) | zero pad]
//   h   = relu(A1 @ W1 + b1)   (MFMA K=96, W1 zero-padded k>=80)
//   msg = h @ W2 + b2          (W2 frags from LDS)
//   h/msg overlaid INTO A1 (cols 0..63): LDS ~21.8KB -> 6 blocks/CU.
//   Segmented reduction reads dst via __shfl (lane `row` holds its tile-row's
//   dst in dcur) — Ds LDS array deleted. The trailing WAR fence is removed:
//   DS ops from one wave execute in order, and the compiler cannot reorder
//   next-iter A1 staging stores past this-iter A1 reduction loads (same
//   array). Correctness of this HW assumption is checked by the harness.
// ---------------------------------------------------------------------------
__global__ __launch_bounds__(256) void edge_kernel(
    const u16* __restrict__ xbf, const float* __restrict__ ef,
    const float* __restrict__ w1, const float* __restrict__ b1,
    const float* __restrict__ w2, const float* __restrict__ b2,
    const uint2* __restrict__ sde, float* __restrict__ agg)
{
    constexpr int S1 = 104;  // A1 row stride (bf16): pad 96->104
    __shared__ u16 A1[4][16 * S1];
    __shared__ u16 W2f[2][4][64 * 8];  // per-lane W2 B-frags (8 KB)

    const int wid  = threadIdx.x >> 6;
    const int lane = threadIdx.x & 63;
    const int q    = lane >> 4;   // quad
    const int c    = lane & 15;   // col within quad
    const int r4   = lane >> 2;   // ef row handled by this lane
    const int p4   = lane & 3;    // ef float4 part

    // W1 B-frags in registers. B[k][n]: n=16*nn+c, k=32*kk+q*8+j
    short8 w1f[3][4];
    #pragma unroll
    for (int kk = 0; kk < 3; ++kk)
        #pragma unroll
        for (int nn = 0; nn < 4; ++nn)
            #pragma unroll
            for (int j = 0; j < 8; ++j) {
                const int k = kk * 32 + q * 8 + j;
                w1f[kk][nn][j] = (k < 80) ? (short)f2bf(w1[k * 64 + nn * 16 + c]) : (short)0;
            }
    // W2 B-frags into LDS once
    if (wid == 0) {
        #pragma unroll
        for (int kk = 0; kk < 2; ++kk)
            #pragma unroll
            for (int nn = 0; nn < 4; ++nn) {
                short8 f;
                #pragma unroll
                for (int j = 0; j < 8; ++j) {
                    const int k = kk * 32 + q * 8 + j;
                    f[j] = (short)f2bf(w2[k * 64 + nn * 16 + c]);
                }
                *(short8*)&W2f[kk][nn][lane * 8] = f;
            }
    }
    float b1v[4], b2v[4];
    #pragma unroll
    for (int nn = 0; nn < 4; ++nn) {
        b1v[nn] = b1[nn * 16 + c];
        b2v[nn] = b2[nn * 16 + c];
    }
    // zero pad region (cols 80..96) once — h/msg writes stay in cols 0..63,
    // ef staging writes cols 64..79, so the pad is never overwritten
    if (q == 1) {
        const short8 z8 = {0, 0, 0, 0, 0, 0, 0, 0};
        *(short8*)&A1[wid][c * S1 + 80] = z8;
        *(short8*)&A1[wid][c * S1 + 88] = z8;
    }
    __syncthreads();

    const floatx4 zero = {0.f, 0.f, 0.f, 0.f};
    const int ntile = NE / 16;  // 50000
    const int stride = gridDim.x * 4;
    int t = blockIdx.x * 4 + wid;

    // ---- prologue: idx for t and t+stride, data for t ----
    uint2 sdB; u32 eB;               // idx regs for NEXT tile
    short8 xa, xb; float4 ev;        // gathered data for CURRENT tile
    int dcur;                        // dst of tile-row (lane&15) — reg-resident
    {
        const uint2 sdA = sde[t * 16 + c];
        const u32  eA  = sde[t * 16 + r4].x;
        dcur = (int)(sdA.y & 0xffffu);
        const int sA = (int)(sdA.y >> 16);
        int tb = t + stride; if (tb >= ntile) tb = ntile - 1;
        sdB = sde[tb * 16 + c];
        eB  = sde[tb * 16 + r4].x;
        const u16* xp = xbf + (size_t)sA * 64 + q * 16;
        xa = *(const short8*)xp;
        xb = *(const short8*)(xp + 8);
        ev = *(const float4*)(ef + (size_t)eA * 16 + p4 * 4);
    }

    for (; t < ntile; t += stride) {
        // ---- stage current tile into LDS (pure copies for x) ----
        u16* arow = &A1[wid][c * S1 + q * 16];
        *(short8*)arow       = xa;
        *(short8*)(arow + 8) = xb;
        {
            short4v e4;
            e4[0] = (short)f2bf(ev.x); e4[1] = (short)f2bf(ev.y);
            e4[2] = (short)f2bf(ev.z); e4[3] = (short)f2bf(ev.w);
            *(short4v*)&A1[wid][r4 * S1 + 64 + p4 * 4] = e4;
        }
        LDS_FENCE();

        // A frags: A[m=c][k=32*kk+q*8+j] — after this, A1 tile data is dead
        short8 a1k[3];
        #pragma unroll
        for (int kk = 0; kk < 3; ++kk)
            a1k[kk] = *(const short8*)&A1[wid][c * S1 + kk * 32 + q * 8];

        // ---- prefetch data for t+stride (idx already resident) ----
        const int dnext = (int)(sdB.y & 0xffffu);
        {
            const int sN = (int)(sdB.y >> 16);
            const u16* xp = xbf + (size_t)sN * 64 + q * 16;
            xa = *(const short8*)xp;
            xb = *(const short8*)(xp + 8);
            ev = *(const float4*)(ef + (size_t)eB * 16 + p4 * 4);
        }
        // idx for t+2*stride
        {
            int tb = t + 2 * stride; if (tb >= ntile) tb = ntile - 1;
            sdB = sde[tb * 16 + c];
            eB  = sde[tb * 16 + r4].x;
        }

        // ---- GEMM1 + bias + relu -> h (bf16) overlaid into A1 cols 0..63 ----
        #pragma unroll
        for (int nn = 0; nn < 4; ++nn) {
            floatx4 acc = MFMA16(a1k[0], w1f[0][nn], zero);
            acc = MFMA16(a1k[1], w1f[1][nn], acc);
            acc = MFMA16(a1k[2], w1f[2][nn], acc);
            #pragma unroll
            for (int r = 0; r < 4; ++r) {
                const float h = fmaxf(acc[r] + b1v[nn], 0.f);
                A1[wid][(q * 4 + r) * S1 + nn * 16 + c] = f2bf(h);
            }
        }
        LDS_FENCE();

        short8 a2k[2];
        #pragma unroll
        for (int kk = 0; kk < 2; ++kk)
            a2k[kk] = *(const short8*)&A1[wid][c * S1 + kk * 32 + q * 8];

        // ---- GEMM2 -> msg (bf16) overlaid into A1 cols 0..63 ----
        #pragma unroll
        for (int nn = 0; nn < 4; ++nn) {
            const short8 wf0 = *(const short8*)&W2f[0][nn][lane * 8];
            const short8 wf1 = *(const short8*)&W2f[1][nn][lane * 8];
            floatx4 mg = MFMA16(a2k[0], wf0, zero);
            mg = MFMA16(a2k[1], wf1, mg);
            #pragma unroll
            for (int r = 0; r < 4; ++r)
                A1[wid][(q * 4 + r) * S1 + nn * 16 + c] = f2bf(mg[r] + b2v[nn]);
        }
        LDS_FENCE();

        // ---- segmented reduction over sorted dst (lane = column) ----
        // dst values come from registers via shuffle: lane `row` holds the
        // dst of tile-row `row` in dcur (replicated across q-groups).
        int dc = __shfl(dcur, 0);
        float acc = bf2f(A1[wid][lane]);
        #pragma unroll
        for (int row = 1; row < 16; ++row) {
            const int d = __shfl(dcur, row);
            const float v = bf2f(A1[wid][row * S1 + lane]);
            if (d == dc) {
                acc += v;
            } else {
                atomicAdd(&agg[(size_t)dc * 64 + lane], acc);
                dc = d;
                acc = v;
            }
        }
        atomicAdd(&agg[(size_t)dc * 64 + lane], acc);

        // no trailing fence: per-wave DS ordering + compiler-visible A1
        // aliasing order the staging stores of the next iteration after the
        // reduction loads above.
        dcur = dnext;
    }
}

// ---------------------------------------------------------------------------
// Node kernel: per 16-node tile (one wave):
//   cat[16x128] = [xbf copy | bf16(agg/(cnt+1e-8))], cnt = hist
//   upd = relu(cat @ W3 + b3); y = upd + x; LayerNorm(y)*gamma+beta -> fp32 out
// ---------------------------------------------------------------------------
__global__ __launch_bounds__(256) void node_kernel(
    const u16* __restrict__ xbf, const float* __restrict__ w3,
    const float* __restrict__ b3, const float* __restrict__ g,
    const float* __restrict__ bb, const float* __restrict__ agg,
    const int* __restrict__ hist, float* __restrict__ out)
{
    constexpr int S3 = 136;  // 128 + 8 pad
    __shared__ u16 Cs[4][16 * S3];

    const int wid  = threadIdx.x >> 6;
    const int lane = threadIdx.x & 63;
    const int q    = lane >> 4;
    const int c    = lane & 15;

    short8 w3f[4][4];
    #pragma unroll
    for (int kk = 0; kk < 4; ++kk)
        #pragma unroll
        for (int nn = 0; nn < 4; ++nn)
            #pragma unroll
            for (int j = 0; j < 8; ++j) {
                const int k = kk * 32 + q * 8 + j;
                w3f[kk][nn][j] = (short)f2bf(w3[k * 64 + nn * 16 + c]);
            }
    float b3v[4], gv[4], bv[4];
    #pragma unroll
    for (int nn = 0; nn < 4; ++nn) {
        b3v[nn] = b3[nn * 16 + c];
        gv[nn]  = g[nn * 16 + c];
        bv[nn]  = bb[nn * 16 + c];
    }

    const floatx4 zero = {0.f, 0.f, 0.f, 0.f};
    const int ntile = NNODES / 16;  // 3125

    for (int t = blockIdx.x * 4 + wid; t < ntile; t += gridDim.x * 4) {
        const int n0 = t * 16;
        const int node = n0 + c;
        u16* crow = &Cs[wid][c * S3];

        if (q < 2) {
            const u16* xp = xbf + (size_t)node * 64 + q * 32;
            *(short8*)&crow[q * 32]      = *(const short8*)xp;
            *(short8*)&crow[q * 32 + 8]  = *(const short8*)(xp + 8);
            *(short8*)&crow[q * 32 + 16] = *(const short8*)(xp + 16);
            *(short8*)&crow[q * 32 + 24] = *(const short8*)(xp + 24);
        } else {
            const int p = q - 2;
            const float inv = 1.0f / ((float)hist[node] + 1e-8f);
            const float* ap = agg + (size_t)node * 64 + p * 32;
            #pragma unroll
            for (int gi = 0; gi < 4; ++gi) {
                const float4 v0 = *(const float4*)(ap + gi * 8);
                const float4 v1 = *(const float4*)(ap + gi * 8 + 4);
                union { short8 s; u32 u[4]; } o;
                o.u[0] = f2bf2(v0.x * inv, v0.y * inv);
                o.u[1] = f2bf2(v0.z * inv, v0.w * inv);
                o.u[2] = f2bf2(v1.x * inv, v1.y * inv);
                o.u[3] = f2bf2(v1.z * inv, v1.w * inv);
                *(short8*)&crow[64 + p * 32 + gi * 8] = o.s;
            }
        }
        LDS_FENCE();

        short8 af[4];
        #pragma unroll
        for (int kk = 0; kk < 4; ++kk)
            af[kk] = *(const short8*)&Cs[wid][c * S3 + kk * 32 + q * 8];

        float y[4][4];
        float s[4]  = {0.f, 0.f, 0.f, 0.f};
        float ss[4] = {0.f, 0.f, 0.f, 0.f};
        #pragma unroll
        for (int nn = 0; nn < 4; ++nn) {
            floatx4 acc = MFMA16(af[0], w3f[0][nn], zero);
            acc = MFMA16(af[1], w3f[1][nn], acc);
            acc = MFMA16(af[2], w3f[2][nn], acc);
            acc = MFMA16(af[3], w3f[3][nn], acc);
            #pragma unroll
            for (int r = 0; r < 4; ++r) {
                const float upd = fmaxf(acc[r] + b3v[nn], 0.f);
                const float xv = bf2f(Cs[wid][(q * 4 + r) * S3 + nn * 16 + c]);
                const float yy = upd + xv;
                y[r][nn] = yy;
                s[r] += yy;
                ss[r] += yy * yy;
            }
        }

        #pragma unroll
        for (int r = 0; r < 4; ++r) {
            float sr = s[r], sq = ss[r];
            #pragma unroll
            for (int off = 1; off < 16; off <<= 1) {
                sr += __shfl_xor(sr, off);
                sq += __shfl_xor(sq, off);
            }
            const float mu  = sr * (1.0f / 64.0f);
            const float var = sq * (1.0f / 64.0f) - mu * mu;
            const float rs  = rsqrtf(var + 1e-5f);
            float* op = out + (size_t)(n0 + q * 4 + r) * 64 + c;
            #pragma unroll
            for (int nn = 0; nn < 4; ++nn)
                op[nn * 16] = (y[r][nn] - mu) * rs * gv[nn] + bv[nn];
        }
    }
}

extern "C" void kernel_launch(void* const* d_in, const int* in_sizes, int n_in,
                              void* d_out, int out_size, void* d_ws, size_t ws_size,
                              hipStream_t stream) {
    const float* x   = (const float*)d_in[0];
    const int*   ei  = (const int*)d_in[1];
    const float* ef  = (const float*)d_in[2];
    const float* w1  = (const float*)d_in[3];
    const float* b1  = (const float*)d_in[4];
    const float* w2  = (const float*)d_in[5];
    const float* b2  = (const float*)d_in[6];
    const float* w3  = (const float*)d_in[7];
    const float* b3  = (const float*)d_in[8];
    const float* g   = (const float*)d_in[9];
    const float* bb  = (const float*)d_in[10];

    // ws layout (u32 units):
    // agg[3.2M] | hist[50k] | cursor[50k] | bsum[256] | bsumx[256](unused)
    // | xbf (3.2M u16 = 1.6M u32) | sde (800k uint2 = 1.6M u32)
    float* agg   = (float*)d_ws;
    int* hist    = (int*)d_ws + 3200000;
    int* cursor  = hist + NNODES;
    int* bsum    = cursor + NNODES;
    int* bsumx   = bsum + 256;
    u16* xbf     = (u16*)(bsumx + 256);
    uint2* sde   = (uint2*)((int*)d_ws + 4900512);

    // memset only hist (200 KB); agg is zeroed inside prep_kernel
    hipMemsetAsync(hist, 0, (size_t)NNODES * sizeof(int), stream);
    prep_kernel<<<3125, 256, 0, stream>>>(x, ei, hist, xbf, agg);
    scan1_kernel<<<NBLK, 256, 0, stream>>>(hist, cursor, bsum);
    scatter_kernel<<<3125, 256, 0, stream>>>(ei, cursor, bsum, sde);
    edge_kernel<<<EDGE_GRID, 256, 0, stream>>>(xbf, ef, w1, b1, w2, b2, sde, agg);
    node_kernel<<<782, 256, 0, stream>>>(xbf, w3, b3, g, bb, agg, hist, (float*)d_out);
}

// Round 13
// 269.738 us; speedup vs baseline: 1.0658x; 1.0658x over previous
//
#include <hip/hip_runtime.h>

typedef unsigned short u16;
typedef unsigned int u32;
typedef short short8 __attribute__((ext_vector_type(8)));
typedef short short4v __attribute__((ext_vector_type(4)));
typedef float floatx4 __attribute__((ext_vector_type(4)));

#define NE 800000
#define NNODES 50000
#define NBLK 196  // ceil(50000/256)

// edge_kernel grid: 1536 = resident set (6 blocks/CU x 256, proven R6).
// LAWS from this session:
//  - R2/R7: never force min-waves via __launch_bounds__ 2nd arg (spills).
//  - R10: never use a global-atomic work queue (contended RMW; 72.8->725us).
//  - R9: direct register-gather loses to LDS staging at matched grid.
//  - R12: per-wave DS ops are in-order; WAR fence after reduction not needed.
//  - R11: non-edge total carries +-5-8us run noise; trust per-kernel counters.
#define EDGE_GRID 1536

#define LDS_FENCE() __asm__ volatile("s_waitcnt lgkmcnt(0)" ::: "memory")

// ---------------------------------------------------------------------------
// bf16 conversions. f2bf (bit-trick) for scalar cases; f2bf2 (native pair
// cvt) where values pair structurally. Both RNE -> bit-identical.
// ---------------------------------------------------------------------------
__device__ __forceinline__ u16 f2bf(float f) {
    union { float f; unsigned int i; } v; v.f = f;
    return (u16)((v.i + 0x7fffu + ((v.i >> 16) & 1u)) >> 16);
}
__device__ __forceinline__ u32 f2bf2(float lo, float hi) {  // [lo | hi<<16]
    u32 r;
    asm("v_cvt_pk_bf16_f32 %0, %1, %2" : "=v"(r) : "v"(lo), "v"(hi));
    return r;
}
__device__ __forceinline__ float bf2f(u16 u) {
    union { unsigned int i; float f; } v; v.i = ((unsigned int)u) << 16; return v.f;
}
__device__ __forceinline__ short8 pack8(const float4 a, const float4 b) {
    union { short8 s; u32 u[4]; } o;
    o.u[0] = f2bf2(a.x, a.y);
    o.u[1] = f2bf2(a.z, a.w);
    o.u[2] = f2bf2(b.x, b.y);
    o.u[3] = f2bf2(b.z, b.w);
    return o.s;
}
__device__ __forceinline__ short8 ld8_bf(const float* __restrict__ p) {
    return pack8(*(const float4*)p, *(const float4*)(p + 4));
}

#define MFMA16(a, b, c) __builtin_amdgcn_mfma_f32_16x16x32_bf16(a, b, c, 0, 0, 0)

// ---------------------------------------------------------------------------
// prep: dst histogram (atomics) + x -> bf16 conversion + agg zeroing, merged.
// ---------------------------------------------------------------------------
__global__ __launch_bounds__(256) void prep_kernel(
    const float* __restrict__ x, const int* __restrict__ ei,
    int* __restrict__ hist, u16* __restrict__ xbf, float* __restrict__ agg)
{
    const int id = blockIdx.x * 256 + threadIdx.x;
    if (id < NE) {
        atomicAdd(&hist[ei[NE + id]], 1);
        // zero agg: 3.2M floats = 800k float4 stores, one per thread
        float4 z; z.x = 0.f; z.y = 0.f; z.z = 0.f; z.w = 0.f;
        *(float4*)&agg[(size_t)id * 4] = z;
    }
    if (id < NNODES * 8) {  // 400000 threads x 8 elems = 3.2M
        *(short8*)&xbf[(size_t)id * 8] = ld8_bf(x + (size_t)id * 8);
    }
}

// per-block exclusive scan (shuffle), local excl + block total
__global__ __launch_bounds__(256) void scan1_kernel(
    const int* __restrict__ hist, int* __restrict__ cursor, int* __restrict__ bsum)
{
    const int i = blockIdx.x * 256 + threadIdx.x;
    const int lane = threadIdx.x & 63;
    const int w = threadIdx.x >> 6;
    const int v = (i < NNODES) ? hist[i] : 0;
    int inc = v;
    #pragma unroll
    for (int o = 1; o < 64; o <<= 1) {
        const int tt = __shfl_up(inc, o);
        if (lane >= o) inc += tt;
    }
    __shared__ int ws[4];
    if (lane == 63) ws[w] = inc;
    __syncthreads();
    int add = 0;
    for (int j = 0; j < w; ++j) add += ws[j];
    const int excl = inc - v + add;
    if (i < NNODES) cursor[i] = excl;
    if (threadIdx.x == 255) bsum[blockIdx.x] = excl + v;
}

// scatter: ONE 8-byte packed record per edge: (.y = src<<16|dst, .x = e).
// The 196-chunk-total exclusive scan is recomputed locally per block in LDS.
__global__ __launch_bounds__(256) void scatter_kernel(
    const int* __restrict__ ei, int* __restrict__ cursor,
    const int* __restrict__ bsum, uint2* __restrict__ sde)
{
    __shared__ int bsx[256];
    __shared__ int ws[4];
    {
        const int tid = threadIdx.x;
        const int lane = tid & 63;
        const int w = tid >> 6;
        const int v = (tid < NBLK) ? bsum[tid] : 0;
        int inc = v;
        #pragma unroll
        for (int o = 1; o < 64; o <<= 1) {
            const int tt = __shfl_up(inc, o);
            if (lane >= o) inc += tt;
        }
        if (lane == 63) ws[w] = inc;
        __syncthreads();
        int add = 0;
        for (int j = 0; j < w; ++j) add += ws[j];
        bsx[tid] = inc - v + add;
    }
    __syncthreads();

    const int e = blockIdx.x * 256 + threadIdx.x;
    if (e < NE) {
        const int dst = ei[NE + e];
        const int p = atomicAdd(&cursor[dst], 1) + bsx[dst >> 8];
        uint2 v;
        v.x = (u32)e;
        v.y = ((u32)ei[e] << 16) | (u32)dst;
        sde[p] = v;
    }
}

// ---------------------------------------------------------------------------
// Edge kernel (R12 base + vectorized LDS dataflow):
//   GEMM1 is computed OPERAND-SWAPPED: hT = W1T @ A1T via mfma(w1f, a1k) —
//   A/B frags share the same lane->(16dim,k) mapping on gfx950, so the
//   existing frag data works unchanged. Output: lane (q,c) holds 4
//   CONSECUTIVE feats (nn*16+q*4+r) of edge c -> h stores become 4x 8-byte
//   writes at [c*S1 + nn*16 + q*4]; a2k reads are byte-identical to before.
//   Bias b1 rides a constant-1.0 K-column (A1 col 80 = 1.0, w1f k=80 = b1).
//   GEMM2 (unswapped) stores msg to an edge-minor overlay [feat*SM + edge]
//   (4x 8-byte writes); the reduction reads its 16 edge values as 4x 8-byte
//   loads (lane = feat) and unpacks in-register.
//   DS wave-ops/tile: ~62 -> ~28 (48 scalar u16 ops eliminated).
// ---------------------------------------------------------------------------
__global__ __launch_bounds__(256) void edge_kernel(
    const u16* __restrict__ xbf, const float* __restrict__ ef,
    const float* __restrict__ w1, const float* __restrict__ b1,
    const float* __restrict__ w2, const float* __restrict__ b2,
    const uint2* __restrict__ sde, float* __restrict__ agg)
{
    constexpr int S1 = 104;  // A1 row stride (bf16): pad 96->104
    constexpr int SM = 20;   // msg overlay stride (u16): idx = feat*SM + edge
    __shared__ u16 A1[4][16 * S1];
    __shared__ u16 W2f[2][4][64 * 8];  // per-lane W2 B-frags (8 KB)

    const int wid  = threadIdx.x >> 6;
    const int lane = threadIdx.x & 63;
    const int q    = lane >> 4;   // quad
    const int c    = lane & 15;   // col within quad
    const int r4   = lane >> 2;   // ef row handled by this lane
    const int p4   = lane & 3;    // ef float4 part

    // W1 frags (A-operand of swapped GEMM1): value w1[k][nn*16+c].
    // k==80 carries b1 (bias via A1's constant-1.0 column 80); k>80 zero.
    short8 w1f[3][4];
    #pragma unroll
    for (int kk = 0; kk < 3; ++kk)
        #pragma unroll
        for (int nn = 0; nn < 4; ++nn)
            #pragma unroll
            for (int j = 0; j < 8; ++j) {
                const int k = kk * 32 + q * 8 + j;
                float wv;
                if (k < 80)       wv = w1[k * 64 + nn * 16 + c];
                else if (k == 80) wv = b1[nn * 16 + c];
                else              wv = 0.f;
                w1f[kk][nn][j] = (short)f2bf(wv);
            }
    // W2 B-frags into LDS once
    if (wid == 0) {
        #pragma unroll
        for (int kk = 0; kk < 2; ++kk)
            #pragma unroll
            for (int nn = 0; nn < 4; ++nn) {
                short8 f;
                #pragma unroll
                for (int j = 0; j < 8; ++j) {
                    const int k = kk * 32 + q * 8 + j;
                    f[j] = (short)f2bf(w2[k * 64 + nn * 16 + c]);
                }
                *(short8*)&W2f[kk][nn][lane * 8] = f;
            }
    }
    float b2v[4];
    #pragma unroll
    for (int nn = 0; nn < 4; ++nn) b2v[nn] = b2[nn * 16 + c];
    __syncthreads();

    const floatx4 zero = {0.f, 0.f, 0.f, 0.f};
    const int ntile = NE / 16;  // 50000
    const int stride = gridDim.x * 4;
    int t = blockIdx.x * 4 + wid;

    // ---- prologue: idx for t and t+stride, data for t ----
    uint2 sdB; u32 eB;               // idx regs for NEXT tile
    short8 xa, xb; float4 ev;        // gathered data for CURRENT tile
    int dcur;                        // dst of tile-row (lane&15) — reg-resident
    {
        const uint2 sdA = sde[t * 16 + c];
        const u32  eA  = sde[t * 16 + r4].x;
        dcur = (int)(sdA.y & 0xffffu);
        const int sA = (int)(sdA.y >> 16);
        int tb = t + stride; if (tb >= ntile) tb = ntile - 1;
        sdB = sde[tb * 16 + c];
        eB  = sde[tb * 16 + r4].x;
        const u16* xp = xbf + (size_t)sA * 64 + q * 16;
        xa = *(const short8*)xp;
        xb = *(const short8*)(xp + 8);
        ev = *(const float4*)(ef + (size_t)eA * 16 + p4 * 4);
    }

    for (; t < ntile; t += stride) {
        // ---- stage current tile into LDS (pure copies for x) ----
        // Pad/bias cols 80..95 are re-staged every tile (the msg overlay
        // below clobbers rows <=12 of this region).
        u16* arow = &A1[wid][c * S1 + q * 16];
        *(short8*)arow       = xa;
        *(short8*)(arow + 8) = xb;
        {
            short4v e4;
            e4[0] = (short)f2bf(ev.x); e4[1] = (short)f2bf(ev.y);
            e4[2] = (short)f2bf(ev.z); e4[3] = (short)f2bf(ev.w);
            *(short4v*)&A1[wid][r4 * S1 + 64 + p4 * 4] = e4;
        }
        if (q == 1) {
            short8 zb = {0, 0, 0, 0, 0, 0, 0, 0};
            zb[0] = (short)0x3F80;  // bf16(1.0): bias column k=80
            *(short8*)&A1[wid][c * S1 + 80] = zb;
            const short8 z8 = {0, 0, 0, 0, 0, 0, 0, 0};
            *(short8*)&A1[wid][c * S1 + 88] = z8;
        }
        LDS_FENCE();

        // A1 frags: row c, k=32*kk+q*8+j — used as B-operand (A1T) below
        short8 a1k[3];
        #pragma unroll
        for (int kk = 0; kk < 3; ++kk)
            a1k[kk] = *(const short8*)&A1[wid][c * S1 + kk * 32 + q * 8];

        // ---- prefetch data for t+stride (idx already resident) ----
        const int dnext = (int)(sdB.y & 0xffffu);
        {
            const int sN = (int)(sdB.y >> 16);
            const u16* xp = xbf + (size_t)sN * 64 + q * 16;
            xa = *(const short8*)xp;
            xb = *(const short8*)(xp + 8);
            ev = *(const float4*)(ef + (size_t)eB * 16 + p4 * 4);
        }
        // idx for t+2*stride
        {
            int tb = t + 2 * stride; if (tb >= ntile) tb = ntile - 1;
            sdB = sde[tb * 16 + c];
            eB  = sde[tb * 16 + r4].x;
        }

        // ---- GEMM1 SWAPPED: hT = W1T @ A1T (+b1 via k=80), relu ----
        // lane (q,c) holds feats nn*16+q*4+r of edge c -> 8-byte stores,
        // h lands in the SAME [edge*S1 + feat] layout a2k expects.
        #pragma unroll
        for (int nn = 0; nn < 4; ++nn) {
            floatx4 acc = MFMA16(w1f[0][nn], a1k[0], zero);
            acc = MFMA16(w1f[1][nn], a1k[1], acc);
            acc = MFMA16(w1f[2][nn], a1k[2], acc);
            uint2 pv;
            pv.x = f2bf2(fmaxf(acc[0], 0.f), fmaxf(acc[1], 0.f));
            pv.y = f2bf2(fmaxf(acc[2], 0.f), fmaxf(acc[3], 0.f));
            *(uint2*)&A1[wid][c * S1 + nn * 16 + q * 4] = pv;
        }
        LDS_FENCE();

        short8 a2k[2];
        #pragma unroll
        for (int kk = 0; kk < 2; ++kk)
            a2k[kk] = *(const short8*)&A1[wid][c * S1 + kk * 32 + q * 8];

        // ---- GEMM2 (unswapped) -> msg C-layout (row=edge q*4+r, col=feat
        // nn*16+c); store edge-minor at [feat*SM + edge] -> 8-byte writes ----
        #pragma unroll
        for (int nn = 0; nn < 4; ++nn) {
            const short8 wf0 = *(const short8*)&W2f[0][nn][lane * 8];
            const short8 wf1 = *(const short8*)&W2f[1][nn][lane * 8];
            floatx4 mg = MFMA16(a2k[0], wf0, zero);
            mg = MFMA16(a2k[1], wf1, mg);
            uint2 pv;
            pv.x = f2bf2(mg[0] + b2v[nn], mg[1] + b2v[nn]);
            pv.y = f2bf2(mg[2] + b2v[nn], mg[3] + b2v[nn]);
            *(uint2*)&A1[wid][(nn * 16 + c) * SM + q * 4] = pv;
        }
        LDS_FENCE();

        // ---- segmented reduction over sorted dst (lane = feat) ----
        // 16 edge values of this feat: 4x 8-byte loads, unpack in-register.
        const uint2 ma = *(const uint2*)&A1[wid][lane * SM];
        const uint2 mb = *(const uint2*)&A1[wid][lane * SM + 4];
        const uint2 mc = *(const uint2*)&A1[wid][lane * SM + 8];
        const uint2 md = *(const uint2*)&A1[wid][lane * SM + 12];
        const u32 w_[8] = {ma.x, ma.y, mb.x, mb.y, mc.x, mc.y, md.x, md.y};
        int dc = __shfl(dcur, 0);
        float acc = bf2f((u16)(w_[0] & 0xffffu));
        #pragma unroll
        for (int row = 1; row < 16; ++row) {
            const int d = __shfl(dcur, row);
            const float v = bf2f((u16)((w_[row >> 1] >> ((row & 1) * 16)) & 0xffffu));
            if (d == dc) {
                acc += v;
            } else {
                atomicAdd(&agg[(size_t)dc * 64 + lane], acc);
                dc = d;
                acc = v;
            }
        }
        atomicAdd(&agg[(size_t)dc * 64 + lane], acc);

        // no trailing fence: per-wave DS ordering (verified R12) orders the
        // next iteration's staging writes after the loads above.
        dcur = dnext;
    }
}

// ---------------------------------------------------------------------------
// Node kernel: per 16-node tile (one wave):
//   cat[16x128] = [xbf copy | bf16(agg/(cnt+1e-8))], cnt = hist
//   upd = relu(cat @ W3 + b3); y = upd + x; LayerNorm(y)*gamma+beta -> fp32 out
// ---------------------------------------------------------------------------
__global__ __launch_bounds__(256) void node_kernel(
    const u16* __restrict__ xbf, const float* __restrict__ w3,
    const float* __restrict__ b3, const float* __restrict__ g,
    const float* __restrict__ bb, const float* __restrict__ agg,
    const int* __restrict__ hist, float* __restrict__ out)
{
    constexpr int S3 = 136;  // 128 + 8 pad
    __shared__ u16 Cs[4][16 * S3];

    const int wid  = threadIdx.x >> 6;
    const int lane = threadIdx.x & 63;
    const int q    = lane >> 4;
    const int c    = lane & 15;

    short8 w3f[4][4];
    #pragma unroll
    for (int kk = 0; kk < 4; ++kk)
        #pragma unroll
        for (int nn = 0; nn < 4; ++nn)
            #pragma unroll
            for (int j = 0; j < 8; ++j) {
                const int k = kk * 32 + q * 8 + j;
                w3f[kk][nn][j] = (short)f2bf(w3[k * 64 + nn * 16 + c]);
            }
    float b3v[4], gv[4], bv[4];
    #pragma unroll
    for (int nn = 0; nn < 4; ++nn) {
        b3v[nn] = b3[nn * 16 + c];
        gv[nn]  = g[nn * 16 + c];
        bv[nn]  = bb[nn * 16 + c];
    }

    const floatx4 zero = {0.f, 0.f, 0.f, 0.f};
    const int ntile = NNODES / 16;  // 3125

    for (int t = blockIdx.x * 4 + wid; t < ntile; t += gridDim.x * 4) {
        const int n0 = t * 16;
        const int node = n0 + c;
        u16* crow = &Cs[wid][c * S3];

        if (q < 2) {
            const u16* xp = xbf + (size_t)node * 64 + q * 32;
            *(short8*)&crow[q * 32]      = *(const short8*)xp;
            *(short8*)&crow[q * 32 + 8]  = *(const short8*)(xp + 8);
            *(short8*)&crow[q * 32 + 16] = *(const short8*)(xp + 16);
            *(short8*)&crow[q * 32 + 24] = *(const short8*)(xp + 24);
        } else {
            const int p = q - 2;
            const float inv = 1.0f / ((float)hist[node] + 1e-8f);
            const float* ap = agg + (size_t)node * 64 + p * 32;
            #pragma unroll
            for (int gi = 0; gi < 4; ++gi) {
                const float4 v0 = *(const float4*)(ap + gi * 8);
                const float4 v1 = *(const float4*)(ap + gi * 8 + 4);
                union { short8 s; u32 u[4]; } o;
                o.u[0] = f2bf2(v0.x * inv, v0.y * inv);
                o.u[1] = f2bf2(v0.z * inv, v0.w * inv);
                o.u[2] = f2bf2(v1.x * inv, v1.y * inv);
                o.u[3] = f2bf2(v1.z * inv, v1.w * inv);
                *(short8*)&crow[64 + p * 32 + gi * 8] = o.s;
            }
        }
        LDS_FENCE();

        short8 af[4];
        #pragma unroll
        for (int kk = 0; kk < 4; ++kk)
            af[kk] = *(const short8*)&Cs[wid][c * S3 + kk * 32 + q * 8];

        float y[4][4];
        float s[4]  = {0.f, 0.f, 0.f, 0.f};
        float ss[4] = {0.f, 0.f, 0.f, 0.f};
        #pragma unroll
        for (int nn = 0; nn < 4; ++nn) {
            floatx4 acc = MFMA16(af[0], w3f[0][nn], zero);
            acc = MFMA16(af[1], w3f[1][nn], acc);
            acc = MFMA16(af[2], w3f[2][nn], acc);
            acc = MFMA16(af[3], w3f[3][nn], acc);
            #pragma unroll
            for (int r = 0; r < 4; ++r) {
                const float upd = fmaxf(acc[r] + b3v[nn], 0.f);
                const float xv = bf2f(Cs[wid][(q * 4 + r) * S3 + nn * 16 + c]);
                const float yy = upd + xv;
                y[r][nn] = yy;
                s[r] += yy;
                ss[r] += yy * yy;
            }
        }

        #pragma unroll
        for (int r = 0; r < 4; ++r) {
            float sr = s[r], sq = ss[r];
            #pragma unroll
            for (int off = 1; off < 16; off <<= 1) {
                sr += __shfl_xor(sr, off);
                sq += __shfl_xor(sq, off);
            }
            const float mu  = sr * (1.0f / 64.0f);
            const float var = sq * (1.0f / 64.0f) - mu * mu;
            const float rs  = rsqrtf(var + 1e-5f);
            float* op = out + (size_t)(n0 + q * 4 + r) * 64 + c;
            #pragma unroll
            for (int nn = 0; nn < 4; ++nn)
                op[nn * 16] = (y[r][nn] - mu) * rs * gv[nn] + bv[nn];
        }
    }
}

extern "C" void kernel_launch(void* const* d_in, const int* in_sizes, int n_in,
                              void* d_out, int out_size, void* d_ws, size_t ws_size,
                              hipStream_t stream) {
    const float* x   = (const float*)d_in[0];
    const int*   ei  = (const int*)d_in[1];
    const float* ef  = (const float*)d_in[2];
    const float* w1  = (const float*)d_in[3];
    const float* b1  = (const float*)d_in[4];
    const float* w2  = (const float*)d_in[5];
    const float* b2  = (const float*)d_in[6];
    const float* w3  = (const float*)d_in[7];
    const float* b3  = (const float*)d_in[8];
    const float* g   = (const float*)d_in[9];
    const float* bb  = (const float*)d_in[10];

    // ws layout (u32 units):
    // agg[3.2M] | hist[50k] | cursor[50k] | bsum[256] | bsumx[256](unused)
    // | xbf (3.2M u16 = 1.6M u32) | sde (800k uint2 = 1.6M u32)
    float* agg   = (float*)d_ws;
    int* hist    = (int*)d_ws + 3200000;
    int* cursor  = hist + NNODES;
    int* bsum    = cursor + NNODES;
    int* bsumx   = bsum + 256;
    u16* xbf     = (u16*)(bsumx + 256);
    uint2* sde   = (uint2*)((int*)d_ws + 4900512);

    // memset only hist (200 KB); agg is zeroed inside prep_kernel
    hipMemsetAsync(hist, 0, (size_t)NNODES * sizeof(int), stream);
    prep_kernel<<<3125, 256, 0, stream>>>(x, ei, hist, xbf, agg);
    scan1_kernel<<<NBLK, 256, 0, stream>>>(hist, cursor, bsum);
    scatter_kernel<<<3125, 256, 0, stream>>>(ei, cursor, bsum, sde);
    edge_kernel<<<EDGE_GRID, 256, 0, stream>>>(xbf, ef, w1, b1, w2, b2, sde, agg);
    node_kernel<<<782, 256, 0, stream>>>(xbf, w3, b3, g, bb, agg, hist, (float*)d_out);
}

// Round 14
// 237.762 us; speedup vs baseline: 1.2091x; 1.1345x over previous
//
#include <hip/hip_runtime.h>

typedef unsigned short u16;
typedef unsigned int u32;
typedef short short8 __attribute__((ext_vector_type(8)));
typedef short short4v __attribute__((ext_vector_type(4)));
typedef float floatx4 __attribute__((ext_vector_type(4)));

#define NE 800000
#define NNODES 50000
#define NBLK 196       // dst chunks (dst>>8), also scan1/sortchunk grid
#define BIN_EDGES 2048
#define BIN_GRID 391   // ceil(800000/2048)
#define CHUNK_CAP 5120 // chunk records cap: E[N]=4096, sigma=64 -> +16 sigma

// edge_kernel grid: 1536 = resident set (6 blocks/CU x 256, proven R6).
// LAWS from this session:
//  - R2/R7: never force min-waves via __launch_bounds__ 2nd arg (spills).
//  - R10: never use a global-atomic work queue (contended RMW; 72.8->725us).
//  - R9: direct register-gather loses to LDS staging at matched grid.
//  - R12: per-wave DS ops are in-order; WAR fence after reduction not needed.
//  - R13: random 8B scatter writes cost a full 64B line each (cross-XCD, no
//    L2 combining): sde scatter wrote 52MB for 6.4MB of records.
#define EDGE_GRID 1536

#define LDS_FENCE() __asm__ volatile("s_waitcnt lgkmcnt(0)" ::: "memory")

// ---------------------------------------------------------------------------
// bf16 conversions. f2bf (bit-trick) for scalar cases; f2bf2 (native pair
// cvt) where values pair structurally. Both RNE -> bit-identical.
// ---------------------------------------------------------------------------
__device__ __forceinline__ u16 f2bf(float f) {
    union { float f; unsigned int i; } v; v.f = f;
    return (u16)((v.i + 0x7fffu + ((v.i >> 16) & 1u)) >> 16);
}
__device__ __forceinline__ u32 f2bf2(float lo, float hi) {  // [lo | hi<<16]
    u32 r;
    asm("v_cvt_pk_bf16_f32 %0, %1, %2" : "=v"(r) : "v"(lo), "v"(hi));
    return r;
}
__device__ __forceinline__ float bf2f(u16 u) {
    union { unsigned int i; float f; } v; v.i = ((unsigned int)u) << 16; return v.f;
}
__device__ __forceinline__ short8 pack8(const float4 a, const float4 b) {
    union { short8 s; u32 u[4]; } o;
    o.u[0] = f2bf2(a.x, a.y);
    o.u[1] = f2bf2(a.z, a.w);
    o.u[2] = f2bf2(b.x, b.y);
    o.u[3] = f2bf2(b.z, b.w);
    return o.s;
}
__device__ __forceinline__ short8 ld8_bf(const float* __restrict__ p) {
    return pack8(*(const float4*)p, *(const float4*)(p + 4));
}

#define MFMA16(a, b, c) __builtin_amdgcn_mfma_f32_16x16x32_bf16(a, b, c, 0, 0, 0)

// ---------------------------------------------------------------------------
// prep: dst histogram (atomics) + x -> bf16 conversion + agg zeroing, merged.
// ---------------------------------------------------------------------------
__global__ __launch_bounds__(256) void prep_kernel(
    const float* __restrict__ x, const int* __restrict__ ei,
    int* __restrict__ hist, u16* __restrict__ xbf, float* __restrict__ agg)
{
    const int id = blockIdx.x * 256 + threadIdx.x;
    if (id < NE) {
        atomicAdd(&hist[ei[NE + id]], 1);
        // zero agg: 3.2M floats = 800k float4 stores, one per thread
        float4 z; z.x = 0.f; z.y = 0.f; z.z = 0.f; z.w = 0.f;
        *(float4*)&agg[(size_t)id * 4] = z;
    }
    if (id < NNODES * 8) {  // 400000 threads x 8 elems = 3.2M
        *(short8*)&xbf[(size_t)id * 8] = ld8_bf(x + (size_t)id * 8);
    }
}

// per-256-chunk totals of hist (per-dst cursor no longer needed: the exact
// within-chunk sort happens in LDS in sortchunk_kernel)
__global__ __launch_bounds__(256) void scan1_kernel(
    const int* __restrict__ hist, int* __restrict__ bsum)
{
    const int i = blockIdx.x * 256 + threadIdx.x;
    const int lane = threadIdx.x & 63;
    const int w = threadIdx.x >> 6;
    const int v = (i < NNODES) ? hist[i] : 0;
    int inc = v;
    #pragma unroll
    for (int o = 1; o < 64; o <<= 1) {
        const int tt = __shfl_up(inc, o);
        if (lane >= o) inc += tt;
    }
    __shared__ int ws[4];
    if (lane == 63) ws[w] = inc;
    __syncthreads();
    int add = 0;
    for (int j = 0; j < w; ++j) add += ws[j];
    if (threadIdx.x == 255) bsum[blockIdx.x] = inc + add;
}

// ---------------------------------------------------------------------------
// bin_kernel (pass 1 of the scatter): each block takes 2048 consecutive
// edges, histograms them over the 196 dst-chunks in LDS, reserves one
// contiguous run per chunk via a single atomicAdd on the 196-entry chunk
// cursor, and writes its records run-contiguously. All writes of a run come
// from ONE block (= one XCD) -> its L2 write-combines the 64B lines, killing
// the 8x write amplification of the per-edge random scatter (R13 law).
// Record: (.x = e, .y = src<<16|dst). Chunk regions are globally dst-chunk-
// major (base = exclusive scan of bsum), so after pass 2 the array is fully
// dst-sorted.
// ---------------------------------------------------------------------------
__global__ __launch_bounds__(256) void bin_kernel(
    const int* __restrict__ ei, const int* __restrict__ bsum,
    int* __restrict__ ccur, uint2* __restrict__ sde)
{
    __shared__ u16 dstv[BIN_EDGES];
    __shared__ u16 srcv[BIN_EDGES];
    __shared__ int h[NBLK];
    __shared__ int basev[NBLK];
    __shared__ int bsx[256];
    __shared__ int ws[4];

    const int tid = threadIdx.x;
    // exclusive scan of the 196 chunk totals -> global chunk bases
    {
        const int lane = tid & 63;
        const int w = tid >> 6;
        const int v = (tid < NBLK) ? bsum[tid] : 0;
        int inc = v;
        #pragma unroll
        for (int o = 1; o < 64; o <<= 1) {
            const int tt = __shfl_up(inc, o);
            if (lane >= o) inc += tt;
        }
        if (lane == 63) ws[w] = inc;
        if (tid < NBLK) h[tid] = 0;
        __syncthreads();
        int add = 0;
        for (int j = 0; j < w; ++j) add += ws[j];
        bsx[tid] = inc - v + add;
    }
    __syncthreads();

    const int e0 = blockIdx.x * BIN_EDGES;
    const int n = (NE - e0 < BIN_EDGES) ? (NE - e0) : BIN_EDGES;

    // stage + chunk histogram
    for (int i = tid; i < n; i += 256) {
        const int d = ei[NE + e0 + i];
        const int s = ei[e0 + i];
        dstv[i] = (u16)d;
        srcv[i] = (u16)s;
        atomicAdd(&h[d >> 8], 1);
    }
    __syncthreads();

    // one contiguous-run reservation per touched chunk
    if (tid < NBLK) {
        const int cnt = h[tid];
        int r = 0;
        if (cnt > 0) r = atomicAdd(&ccur[tid], cnt);
        basev[tid] = bsx[tid] + r;
        h[tid] = 0;  // reuse as rank counter
    }
    __syncthreads();

    // write records at base + local rank (order within run irrelevant)
    for (int i = tid; i < n; i += 256) {
        const int d = dstv[i];
        const int kb = d >> 8;
        const int rank = atomicAdd(&h[kb], 1);
        uint2 v;
        v.x = (u32)(e0 + i);
        v.y = ((u32)srcv[i] << 16) | (u32)d;
        sde[basev[kb] + rank] = v;
    }
}

// ---------------------------------------------------------------------------
// sortchunk_kernel (pass 2): one block per dst-chunk. Loads the chunk's
// records, LDS counting-sort by dst&255, writes the region back fully
// coalesced. If a chunk ever exceeded CHUNK_CAP it is left bin-ordered —
// edge_kernel's segmented reduce is correct for ANY order (sortedness only
// reduces the atomic count), so this fallback is always safe.
// ---------------------------------------------------------------------------
__global__ __launch_bounds__(256) void sortchunk_kernel(
    const int* __restrict__ bsum, uint2* __restrict__ sde)
{
    __shared__ uint2 rec[CHUNK_CAP];
    __shared__ int h[256];
    __shared__ int bsx[256];
    __shared__ int ws[4];

    const int tid = threadIdx.x;
    {
        const int lane = tid & 63;
        const int w = tid >> 6;
        const int v = (tid < NBLK) ? bsum[tid] : 0;
        int inc = v;
        #pragma unroll
        for (int o = 1; o < 64; o <<= 1) {
            const int tt = __shfl_up(inc, o);
            if (lane >= o) inc += tt;
        }
        if (lane == 63) ws[w] = inc;
        h[tid] = 0;
        __syncthreads();
        int add = 0;
        for (int j = 0; j < w; ++j) add += ws[j];
        bsx[tid] = inc - v + add;
    }
    __syncthreads();

    const int B = bsx[blockIdx.x];
    const int N = bsum[blockIdx.x];
    if (N > CHUNK_CAP) return;  // safe fallback: leave bin-ordered

    // per-local-dst histogram
    for (int i = tid; i < N; i += 256)
        atomicAdd(&h[sde[B + i].y & 255], 1);
    __syncthreads();

    // exclusive scan h[256] in place -> running cursors
    {
        const int lane = tid & 63;
        const int w = tid >> 6;
        const int v = h[tid];
        int inc = v;
        #pragma unroll
        for (int o = 1; o < 64; o <<= 1) {
            const int tt = __shfl_up(inc, o);
            if (lane >= o) inc += tt;
        }
        if (lane == 63) ws[w] = inc;
        __syncthreads();
        int add = 0;
        for (int j = 0; j < w; ++j) add += ws[j];
        h[tid] = inc - v + add;
    }
    __syncthreads();

    // scatter into LDS at exact sorted positions (re-read is L2-hot)
    for (int i = tid; i < N; i += 256) {
        const uint2 r = sde[B + i];
        const int pos = atomicAdd(&h[r.y & 255], 1);
        rec[pos] = r;
    }
    __syncthreads();

    // coalesced write-back
    for (int i = tid; i < N; i += 256)
        sde[B + i] = rec[i];
}

// ---------------------------------------------------------------------------
// Edge kernel (R13, unchanged): swapped GEMM1 (hT = W1T@A1T, bias via
// constant-1.0 K-column), vectorized 8-byte LDS stores, edge-minor msg
// overlay, register-resident dst reduction, no trailing WAR fence.
// ---------------------------------------------------------------------------
__global__ __launch_bounds__(256) void edge_kernel(
    const u16* __restrict__ xbf, const float* __restrict__ ef,
    const float* __restrict__ w1, const float* __restrict__ b1,
    const float* __restrict__ w2, const float* __restrict__ b2,
    const uint2* __restrict__ sde, float* __restrict__ agg)
{
    constexpr int S1 = 104;  // A1 row stride (bf16): pad 96->104
    constexpr int SM = 20;   // msg overlay stride (u16): idx = feat*SM + edge
    __shared__ u16 A1[4][16 * S1];
    __shared__ u16 W2f[2][4][64 * 8];  // per-lane W2 B-frags (8 KB)

    const int wid  = threadIdx.x >> 6;
    const int lane = threadIdx.x & 63;
    const int q    = lane >> 4;   // quad
    const int c    = lane & 15;   // col within quad
    const int r4   = lane >> 2;   // ef row handled by this lane
    const int p4   = lane & 3;    // ef float4 part

    // W1 frags (A-operand of swapped GEMM1): value w1[k][nn*16+c].
    // k==80 carries b1 (bias via A1's constant-1.0 column 80); k>80 zero.
    short8 w1f[3][4];
    #pragma unroll
    for (int kk = 0; kk < 3; ++kk)
        #pragma unroll
        for (int nn = 0; nn < 4; ++nn)
            #pragma unroll
            for (int j = 0; j < 8; ++j) {
                const int k = kk * 32 + q * 8 + j;
                float wv;
                if (k < 80)       wv = w1[k * 64 + nn * 16 + c];
                else if (k == 80) wv = b1[nn * 16 + c];
                else              wv = 0.f;
                w1f[kk][nn][j] = (short)f2bf(wv);
            }
    // W2 B-frags into LDS once
    if (wid == 0) {
        #pragma unroll
        for (int kk = 0; kk < 2; ++kk)
            #pragma unroll
            for (int nn = 0; nn < 4; ++nn) {
                short8 f;
                #pragma unroll
                for (int j = 0; j < 8; ++j) {
                    const int k = kk * 32 + q * 8 + j;
                    f[j] = (short)f2bf(w2[k * 64 + nn * 16 + c]);
                }
                *(short8*)&W2f[kk][nn][lane * 8] = f;
            }
    }
    float b2v[4];
    #pragma unroll
    for (int nn = 0; nn < 4; ++nn) b2v[nn] = b2[nn * 16 + c];
    __syncthreads();

    const floatx4 zero = {0.f, 0.f, 0.f, 0.f};
    const int ntile = NE / 16;  // 50000
    const int stride = gridDim.x * 4;
    int t = blockIdx.x * 4 + wid;

    // ---- prologue: idx for t and t+stride, data for t ----
    uint2 sdB; u32 eB;               // idx regs for NEXT tile
    short8 xa, xb; float4 ev;        // gathered data for CURRENT tile
    int dcur;                        // dst of tile-row (lane&15) — reg-resident
    {
        const uint2 sdA = sde[t * 16 + c];
        const u32  eA  = sde[t * 16 + r4].x;
        dcur = (int)(sdA.y & 0xffffu);
        const int sA = (int)(sdA.y >> 16);
        int tb = t + stride; if (tb >= ntile) tb = ntile - 1;
        sdB = sde[tb * 16 + c];
        eB  = sde[tb * 16 + r4].x;
        const u16* xp = xbf + (size_t)sA * 64 + q * 16;
        xa = *(const short8*)xp;
        xb = *(const short8*)(xp + 8);
        ev = *(const float4*)(ef + (size_t)eA * 16 + p4 * 4);
    }

    for (; t < ntile; t += stride) {
        // ---- stage current tile into LDS (pure copies for x) ----
        // Pad/bias cols 80..95 are re-staged every tile (the msg overlay
        // below clobbers rows <=12 of this region).
        u16* arow = &A1[wid][c * S1 + q * 16];
        *(short8*)arow       = xa;
        *(short8*)(arow + 8) = xb;
        {
            short4v e4;
            e4[0] = (short)f2bf(ev.x); e4[1] = (short)f2bf(ev.y);
            e4[2] = (short)f2bf(ev.z); e4[3] = (short)f2bf(ev.w);
            *(short4v*)&A1[wid][r4 * S1 + 64 + p4 * 4] = e4;
        }
        if (q == 1) {
            short8 zb = {0, 0, 0, 0, 0, 0, 0, 0};
            zb[0] = (short)0x3F80;  // bf16(1.0): bias column k=80
            *(short8*)&A1[wid][c * S1 + 80] = zb;
            const short8 z8 = {0, 0, 0, 0, 0, 0, 0, 0};
            *(short8*)&A1[wid][c * S1 + 88] = z8;
        }
        LDS_FENCE();

        // A1 frags: row c, k=32*kk+q*8+j — used as B-operand (A1T) below
        short8 a1k[3];
        #pragma unroll
        for (int kk = 0; kk < 3; ++kk)
            a1k[kk] = *(const short8*)&A1[wid][c * S1 + kk * 32 + q * 8];

        // ---- prefetch data for t+stride (idx already resident) ----
        const int dnext = (int)(sdB.y & 0xffffu);
        {
            const int sN = (int)(sdB.y >> 16);
            const u16* xp = xbf + (size_t)sN * 64 + q * 16;
            xa = *(const short8*)xp;
            xb = *(const short8*)(xp + 8);
            ev = *(const float4*)(ef + (size_t)eB * 16 + p4 * 4);
        }
        // idx for t+2*stride
        {
            int tb = t + 2 * stride; if (tb >= ntile) tb = ntile - 1;
            sdB = sde[tb * 16 + c];
            eB  = sde[tb * 16 + r4].x;
        }

        // ---- GEMM1 SWAPPED: hT = W1T @ A1T (+b1 via k=80), relu ----
        #pragma unroll
        for (int nn = 0; nn < 4; ++nn) {
            floatx4 acc = MFMA16(w1f[0][nn], a1k[0], zero);
            acc = MFMA16(w1f[1][nn], a1k[1], acc);
            acc = MFMA16(w1f[2][nn], a1k[2], acc);
            uint2 pv;
            pv.x = f2bf2(fmaxf(acc[0], 0.f), fmaxf(acc[1], 0.f));
            pv.y = f2bf2(fmaxf(acc[2], 0.f), fmaxf(acc[3], 0.f));
            *(uint2*)&A1[wid][c * S1 + nn * 16 + q * 4] = pv;
        }
        LDS_FENCE();

        short8 a2k[2];
        #pragma unroll
        for (int kk = 0; kk < 2; ++kk)
            a2k[kk] = *(const short8*)&A1[wid][c * S1 + kk * 32 + q * 8];

        // ---- GEMM2 (unswapped) -> edge-minor msg overlay [feat*SM + edge] ----
        #pragma unroll
        for (int nn = 0; nn < 4; ++nn) {
            const short8 wf0 = *(const short8*)&W2f[0][nn][lane * 8];
            const short8 wf1 = *(const short8*)&W2f[1][nn][lane * 8];
            floatx4 mg = MFMA16(a2k[0], wf0, zero);
            mg = MFMA16(a2k[1], wf1, mg);
            uint2 pv;
            pv.x = f2bf2(mg[0] + b2v[nn], mg[1] + b2v[nn]);
            pv.y = f2bf2(mg[2] + b2v[nn], mg[3] + b2v[nn]);
            *(uint2*)&A1[wid][(nn * 16 + c) * SM + q * 4] = pv;
        }
        LDS_FENCE();

        // ---- segmented reduction over sorted dst (lane = feat) ----
        const uint2 ma = *(const uint2*)&A1[wid][lane * SM];
        const uint2 mb = *(const uint2*)&A1[wid][lane * SM + 4];
        const uint2 mc = *(const uint2*)&A1[wid][lane * SM + 8];
        const uint2 md = *(const uint2*)&A1[wid][lane * SM + 12];
        const u32 w_[8] = {ma.x, ma.y, mb.x, mb.y, mc.x, mc.y, md.x, md.y};
        int dc = __shfl(dcur, 0);
        float acc = bf2f((u16)(w_[0] & 0xffffu));
        #pragma unroll
        for (int row = 1; row < 16; ++row) {
            const int d = __shfl(dcur, row);
            const float v = bf2f((u16)((w_[row >> 1] >> ((row & 1) * 16)) & 0xffffu));
            if (d == dc) {
                acc += v;
            } else {
                atomicAdd(&agg[(size_t)dc * 64 + lane], acc);
                dc = d;
                acc = v;
            }
        }
        atomicAdd(&agg[(size_t)dc * 64 + lane], acc);

        // no trailing fence: per-wave DS ordering (verified R12) orders the
        // next iteration's staging writes after the loads above.
        dcur = dnext;
    }
}

// ---------------------------------------------------------------------------
// Node kernel: per 16-node tile (one wave):
//   cat[16x128] = [xbf copy | bf16(agg/(cnt+1e-8))], cnt = hist
//   upd = relu(cat @ W3 + b3); y = upd + x; LayerNorm(y)*gamma+beta -> fp32 out
// ---------------------------------------------------------------------------
__global__ __launch_bounds__(256) void node_kernel(
    const u16* __restrict__ xbf, const float* __restrict__ w3,
    const float* __restrict__ b3, const float* __restrict__ g,
    const float* __restrict__ bb, const float* __restrict__ agg,
    const int* __restrict__ hist, float* __restrict__ out)
{
    constexpr int S3 = 136;  // 128 + 8 pad
    __shared__ u16 Cs[4][16 * S3];

    const int wid  = threadIdx.x >> 6;
    const int lane = threadIdx.x & 63;
    const int q    = lane >> 4;
    const int c    = lane & 15;

    short8 w3f[4][4];
    #pragma unroll
    for (int kk = 0; kk < 4; ++kk)
        #pragma unroll
        for (int nn = 0; nn < 4; ++nn)
            #pragma unroll
            for (int j = 0; j < 8; ++j) {
                const int k = kk * 32 + q * 8 + j;
                w3f[kk][nn][j] = (short)f2bf(w3[k * 64 + nn * 16 + c]);
            }
    float b3v[4], gv[4], bv[4];
    #pragma unroll
    for (int nn = 0; nn < 4; ++nn) {
        b3v[nn] = b3[nn * 16 + c];
        gv[nn]  = g[nn * 16 + c];
        bv[nn]  = bb[nn * 16 + c];
    }

    const floatx4 zero = {0.f, 0.f, 0.f, 0.f};
    const int ntile = NNODES / 16;  // 3125

    for (int t = blockIdx.x * 4 + wid; t < ntile; t += gridDim.x * 4) {
        const int n0 = t * 16;
        const int node = n0 + c;
        u16* crow = &Cs[wid][c * S3];

        if (q < 2) {
            const u16* xp = xbf + (size_t)node * 64 + q * 32;
            *(short8*)&crow[q * 32]      = *(const short8*)xp;
            *(short8*)&crow[q * 32 + 8]  = *(const short8*)(xp + 8);
            *(short8*)&crow[q * 32 + 16] = *(const short8*)(xp + 16);
            *(short8*)&crow[q * 32 + 24] = *(const short8*)(xp + 24);
        } else {
            const int p = q - 2;
            const float inv = 1.0f / ((float)hist[node] + 1e-8f);
            const float* ap = agg + (size_t)node * 64 + p * 32;
            #pragma unroll
            for (int gi = 0; gi < 4; ++gi) {
                const float4 v0 = *(const float4*)(ap + gi * 8);
                const float4 v1 = *(const float4*)(ap + gi * 8 + 4);
                union { short8 s; u32 u[4]; } o;
                o.u[0] = f2bf2(v0.x * inv, v0.y * inv);
                o.u[1] = f2bf2(v0.z * inv, v0.w * inv);
                o.u[2] = f2bf2(v1.x * inv, v1.y * inv);
                o.u[3] = f2bf2(v1.z * inv, v1.w * inv);
                *(short8*)&crow[64 + p * 32 + gi * 8] = o.s;
            }
        }
        LDS_FENCE();

        short8 af[4];
        #pragma unroll
        for (int kk = 0; kk < 4; ++kk)
            af[kk] = *(const short8*)&Cs[wid][c * S3 + kk * 32 + q * 8];

        float y[4][4];
        float s[4]  = {0.f, 0.f, 0.f, 0.f};
        float ss[4] = {0.f, 0.f, 0.f, 0.f};
        #pragma unroll
        for (int nn = 0; nn < 4; ++nn) {
            floatx4 acc = MFMA16(af[0], w3f[0][nn], zero);
            acc = MFMA16(af[1], w3f[1][nn], acc);
            acc = MFMA16(af[2], w3f[2][nn], acc);
            acc = MFMA16(af[3], w3f[3][nn], acc);
            #pragma unroll
            for (int r = 0; r < 4; ++r) {
                const float upd = fmaxf(acc[r] + b3v[nn], 0.f);
                const float xv = bf2f(Cs[wid][(q * 4 + r) * S3 + nn * 16 + c]);
                const float yy = upd + xv;
                y[r][nn] = yy;
                s[r] += yy;
                ss[r] += yy * yy;
            }
        }

        #pragma unroll
        for (int r = 0; r < 4; ++r) {
            float sr = s[r], sq = ss[r];
            #pragma unroll
            for (int off = 1; off < 16; off <<= 1) {
                sr += __shfl_xor(sr, off);
                sq += __shfl_xor(sq, off);
            }
            const float mu  = sr * (1.0f / 64.0f);
            const float var = sq * (1.0f / 64.0f) - mu * mu;
            const float rs  = rsqrtf(var + 1e-5f);
            float* op = out + (size_t)(n0 + q * 4 + r) * 64 + c;
            #pragma unroll
            for (int nn = 0; nn < 4; ++nn)
                op[nn * 16] = (y[r][nn] - mu) * rs * gv[nn] + bv[nn];
        }
    }
}

extern "C" void kernel_launch(void* const* d_in, const int* in_sizes, int n_in,
                              void* d_out, int out_size, void* d_ws, size_t ws_size,
                              hipStream_t stream) {
    const float* x   = (const float*)d_in[0];
    const int*   ei  = (const int*)d_in[1];
    const float* ef  = (const float*)d_in[2];
    const float* w1  = (const float*)d_in[3];
    const float* b1  = (const float*)d_in[4];
    const float* w2  = (const float*)d_in[5];
    const float* b2  = (const float*)d_in[6];
    const float* w3  = (const float*)d_in[7];
    const float* b3  = (const float*)d_in[8];
    const float* g   = (const float*)d_in[9];
    const float* bb  = (const float*)d_in[10];

    // ws layout (u32 units):
    // agg[3.2M] | hist[50k] | cursor[50k] (first 196 reused as chunk cursor)
    // | bsum[256] | bsumx[256](unused) | xbf (1.6M u32) | sde (1.6M u32)
    float* agg   = (float*)d_ws;
    int* hist    = (int*)d_ws + 3200000;
    int* cursor  = hist + NNODES;
    int* bsum    = cursor + NNODES;
    int* bsumx   = bsum + 256;
    u16* xbf     = (u16*)(bsumx + 256);
    uint2* sde   = (uint2*)((int*)d_ws + 4900512);
    (void)bsumx;

    // memset hist + chunk cursor (cursor[0..255])
    hipMemsetAsync(hist, 0, (size_t)(NNODES + 256) * sizeof(int), stream);
    prep_kernel<<<3125, 256, 0, stream>>>(x, ei, hist, xbf, agg);
    scan1_kernel<<<NBLK, 256, 0, stream>>>(hist, bsum);
    bin_kernel<<<BIN_GRID, 256, 0, stream>>>(ei, bsum, cursor, sde);
    sortchunk_kernel<<<NBLK, 256, 0, stream>>>(bsum, sde);
    edge_kernel<<<EDGE_GRID, 256, 0, stream>>>(xbf, ef, w1, b1, w2, b2, sde, agg);
    node_kernel<<<782, 256, 0, stream>>>(xbf, w3, b3, g, bb, agg, hist, (float*)d_out);
}